// Round 21
// baseline (90.162 us; speedup 1.0000x reference)
//
#include <hip/hip_runtime.h>
#include <math.h>

namespace {

constexpr int HW  = 196;
constexpr int HWP = 224;
constexpr int OC  = 2048;
constexpr float TEMP   = 0.35355339059327373f;  // 1/sqrt(KEY_DIM)
constexpr float INV196 = 1.0f / 196.0f;

typedef __attribute__((ext_vector_type(8))) _Float16 half8;
typedef __attribute__((ext_vector_type(4))) float f32x4;

__device__ __forceinline__ void gload_lds16(const void* g, void* l) {
  __builtin_amdgcn_global_load_lds(
      (const __attribute__((address_space(1))) void*)g,
      (__attribute__((address_space(3))) void*)l, 16, 0, 0);
}

#define MFMAH(a, b, c) __builtin_amdgcn_mfma_f32_16x16x32_f16((a), (b), (c), 0, 0, 0)
#define SBAR0() __builtin_amdgcn_sched_barrier(0)

// ================= K1: WvA prep (512 blocks) || pool (4096 blocks, XCD-affine) =================
__global__ __launch_bounds__(256) void fat_prep(
    const float* __restrict__ x, const float* __restrict__ Wv,
    _Float16* __restrict__ WvA,
    _Float16* __restrict__ xpH, float* __restrict__ xm) {
  __shared__ float tl[8][264];
  int bid = blockIdx.x;
  int t = threadIdx.x;
  if (bid < 512) {
    int kk = bid >> 5;
    int rq = bid & 31;
    int w = t >> 6, lane = t & 63;
    int r = rq * 4 + w;
    int oc = r * 16 + (lane & 15);
    int c0 = kk * 32 + (lane >> 4) * 8;
    const float* src = Wv + (size_t)oc * 512 + c0;
    float4 v0 = *(const float4*)src;
    float4 v1 = *(const float4*)(src + 4);
    float vals[8] = {v0.x, v0.y, v0.z, v0.w, v1.x, v1.y, v1.z, v1.w};
    half8 hi, lo;
    #pragma unroll
    for (int e = 0; e < 8; ++e) {
      _Float16 h = (_Float16)vals[e];
      hi[e] = h;
      lo[e] = (_Float16)(vals[e] - (float)h);
    }
    *(half8*)(WvA + ((size_t)(kk * 2 + 0) * 128 + r) * 512 + lane * 8) = hi;
    *(half8*)(WvA + ((size_t)(kk * 2 + 1) * 128 + r) * 512 + lane * 8) = lo;
  } else {
    int pb = bid - 512;
    int nd = (((pb >> 9) & 7) << 3) | (pb & 7);   // XCD-affine
    int cg = (pb >> 3) & 63;
    int n = nd >> 5, d = nd & 31;
    int c0 = cg * 8;
    int cl = t >> 5, s = t & 31;
    const float* xr = x + (((size_t)(n * 512 + c0 + cl)) * 32 + d) * 256;
    float4 va = *(const float4*)(xr + s * 8);
    float4 vb = *(const float4*)(xr + s * 8 + 4);
    *(float4*)&tl[cl][s * 8] = va;
    *(float4*)&tl[cl][s * 8 + 4] = vb;
    float rs = va.x + va.y + va.z + va.w + vb.x + vb.y + vb.z + vb.w;
    #pragma unroll
    for (int off = 16; off; off >>= 1) rs += __shfl_xor(rs, off, 32);
    if (s == 0) xm[nd * 512 + c0 + cl] = rs * (1.0f / 256.0f);
    __syncthreads();
    if (t < HWP) {
      int hw = t;
      half8 hi;
      if (hw < HW) {
        int y = hw / 14, xx = hw - y * 14;
        #pragma unroll
        for (int c = 0; c < 8; ++c) {
          const float* q = &tl[c][y * 16 + xx];
          float val = (q[0] + q[1] + q[2] + q[16] + q[17] + q[18] +
                       q[32] + q[33] + q[34]) * (1.0f / 9.0f);
          hi[c] = (_Float16)val;
        }
      } else {
        #pragma unroll
        for (int c = 0; c < 8; ++c) hi[c] = (_Float16)0.f;
      }
      *(half8*)(xpH + ((size_t)nd * HWP + hw) * 512 + c0) = hi;
    }
  }
}

// ---------------- attn dots: dot[nd][o][hw] = qw[o] . xp_hi[hw]  (4 lanes per hw) ----------------
__global__ __launch_bounds__(256) void attn_dots(
    const float* __restrict__ Wq, const float* __restrict__ Wk,
    const float* __restrict__ xm,
    const _Float16* __restrict__ xpH, float* __restrict__ dotb) {
  int b = blockIdx.x;
  int nd = b >> 2, ch = b & 3;
  int t = threadIdx.x;
  __shared__ float xs[512];
  __shared__ float qsA[32];
  __shared__ float qw[2048];
  xs[t] = xm[nd * 512 + t];
  xs[t + 256] = xm[nd * 512 + t + 256];
  __syncthreads();
  {
    int k = t >> 3, j = t & 7;
    float p = 0.f;
    #pragma unroll 8
    for (int c = j; c < 512; c += 8) p = fmaf(Wq[k * 512 + c], xs[c], p);
    p += __shfl_xor(p, 4, 8);
    p += __shfl_xor(p, 2, 8);
    p += __shfl_xor(p, 1, 8);
    if (j == 0) qsA[k] = p;
  }
  __syncthreads();
  {
    int o = t >> 6;
    int c0 = (t & 63) * 8;
    float q[8];
    #pragma unroll
    for (int kd = 0; kd < 8; ++kd) q[kd] = qsA[o * 8 + kd];
    #pragma unroll
    for (int e = 0; e < 8; ++e) {
      float a = 0.f;
      #pragma unroll
      for (int kd = 0; kd < 8; ++kd)
        a = fmaf(q[kd], Wk[(size_t)(o * 8 + kd) * 512 + c0 + e], a);
      qw[o * 512 + c0 + e] = a;
    }
  }
  __syncthreads();
  if (t < 224) {
    int hwl = t >> 2, q = t & 3;
    int hw = ch * 56 + hwl;
    const _Float16* rh = xpH + ((size_t)nd * HWP + hw) * 512;
    float d0 = 0.f, d1 = 0.f, d2 = 0.f, d3 = 0.f;
    #pragma unroll
    for (int k = 0; k < 16; ++k) {
      int cb = q * 8 + k * 32;           // interleaved c-blocks: conflict-free qw banks
      half8 h = *(const half8*)(rh + cb);
      #pragma unroll
      for (int e = 0; e < 8; ++e) {
        float xv = (float)h[e];
        d0 = fmaf(qw[cb + e], xv, d0);
        d1 = fmaf(qw[512 + cb + e], xv, d1);
        d2 = fmaf(qw[1024 + cb + e], xv, d2);
        d3 = fmaf(qw[1536 + cb + e], xv, d3);
      }
    }
    d0 += __shfl_xor(d0, 1, 4); d0 += __shfl_xor(d0, 2, 4);
    d1 += __shfl_xor(d1, 1, 4); d1 += __shfl_xor(d1, 2, 4);
    d2 += __shfl_xor(d2, 1, 4); d2 += __shfl_xor(d2, 2, 4);
    d3 += __shfl_xor(d3, 1, 4); d3 += __shfl_xor(d3, 2, 4);
    float r = (q == 0) ? d0 : (q == 1) ? d1 : (q == 2) ? d2 : d3;
    dotb[((size_t)nd * 4 + q) * HWP + hw] = r * TEMP;
  }
}

// ---------------- moments + inline softmax + attention-weighted sum (1-product f16 MFMA) ----------
// r20's single-barrier 3-buffer pipeline, wave re-split for occupancy: wave = 1 oc-row x 13 j
// (acc 52 AGPR + ~60 arch < 128 unified -> 4 waves/SIMD, 2x r20's occupancy).
// Grid 2048 = 64 nd x 32 ob2; block = 64 oc x 208 hw; o = ob2>>3.
// Ledger: region kk = [stage(kk+2) x4][A(kk+2) x1]. Newer-than-stage(kk) at barrier-A(kk) =
// A(kk)1 + s(kk+1)4 + A(kk+1)1 = 6 -> steady vmcnt(6) (same value r20 validated); kk=15 -> 0.
__global__ __launch_bounds__(256, 2) void moments_mfma(
    const _Float16* __restrict__ WvA, const _Float16* __restrict__ xpH,
    const float* __restrict__ dotb, float* __restrict__ attn_out,
    float* __restrict__ S1, float* __restrict__ S2, float* __restrict__ S3) {
  int bid = blockIdx.x;
  int ob2 = (bid >> 3) & 31;
  int nd = ((bid >> 8) << 3) | (bid & 7);
  int o = ob2 >> 3;
  int t = threadIdx.x;
  int w = t >> 6, lane = t & 63;
  int rbase = ob2 * 4 + w;               // this wave's single oc-row (16 oc)
  __shared__ char ldsb[39936];           // 3 x 13312 B buffers: [j(13)][granule(64)][16B]
  __shared__ float attn_sh[HWP];
  __shared__ float redm[4];
  __shared__ float reds[4];
  const _Float16* xph = xpH + (size_t)nd * HWP * 512;

  float vdot = (t < HW) ? dotb[((size_t)nd * 4 + o) * HWP + t] : -3.0e38f;

  f32x4 acc[13];
  #pragma unroll
  for (int j = 0; j < 13; ++j) acc[j] = (f32x4){0.f, 0.f, 0.f, 0.f};

  // stage one 13312B kk-tile: every wave issues exactly 4 gload_lds instructions
  auto stage = [&](char* buf, int kk) {
    #pragma unroll
    for (int i = 0; i < 3; ++i) {
      int G = i * 256 + t;
      int j = G >> 6, g = G & 63;
      int hwl = g & 15, bb = g >> 4;
      const _Float16* src = xph + (size_t)(j * 16 + hwl) * 512 + kk * 32 + bb * 8;
      gload_lds16((const void*)src, (void*)(buf + G * 16));
    }
    if (lane < 16) {
      int G = 768 + w * 16 + lane;
      int g = G & 63;
      int hwl = g & 15, bb = g >> 4;
      const _Float16* src = xph + (size_t)(12 * 16 + hwl) * 512 + kk * 32 + bb * 8;
      gload_lds16((const void*)src, (void*)(buf + G * 16));
    }
  };

  stage(ldsb, 0);                        // s(0) -> buf0: 4 vmem/wave
  SBAR0();
  stage(ldsb + 13312, 1);                // s(1) -> buf1: 4
  SBAR0();
  half8 Ah0, Ah1;
  Ah0 = *(const half8*)(WvA + ((size_t)(0 * 2 + 0) * 128 + rbase) * 512 + lane * 8);  // A(0): 1
  Ah1 = *(const half8*)(WvA + ((size_t)(1 * 2 + 0) * 128 + rbase) * 512 + lane * 8);  // A(1): 1
  SBAR0();

  // ---- inline softmax (exact division); lgkm-only barriers keep vmem loads in flight ----
  {
    float m = vdot;
    #pragma unroll
    for (int off = 32; off; off >>= 1) m = fmaxf(m, __shfl_xor(m, off, 64));
    if (lane == 0) redm[w] = m;
    asm volatile("s_waitcnt lgkmcnt(0)" ::: "memory");
    __builtin_amdgcn_s_barrier();
    float bm = fmaxf(fmaxf(redm[0], redm[1]), fmaxf(redm[2], redm[3]));
    float e = (t < HW) ? expf(vdot - bm) : 0.f;
    float s = e;
    #pragma unroll
    for (int off = 32; off; off >>= 1) s += __shfl_xor(s, off, 64);
    if (lane == 0) reds[w] = s;
    asm volatile("s_waitcnt lgkmcnt(0)" ::: "memory");
    __builtin_amdgcn_s_barrier();
    float bs = reds[0] + reds[1] + reds[2] + reds[3];
    float a = (t < HW) ? (e / bs) : 0.f;
    if (t < HWP) attn_sh[t] = a;
    if ((ob2 & 7) == 0 && t < HW) {
      int n = nd >> 5, d = nd & 31;
      attn_out[(((size_t)n * 4 + o) * 32 + d) * HW + t] = a;
    }
  }

  // ---- main pipelined loop: ONE barrier per iteration ----
  #pragma unroll
  for (int kk = 0; kk < 16; ++kk) {
    if (kk == 15) {
      asm volatile("s_waitcnt vmcnt(0) lgkmcnt(0)" ::: "memory");
    } else {
      asm volatile("s_waitcnt vmcnt(6) lgkmcnt(0)" ::: "memory");
    }
    __builtin_amdgcn_s_barrier();
    SBAR0();
    __builtin_amdgcn_s_setprio(1);
    const char* bp = ldsb + (kk % 3) * 13312;
    if ((kk & 1) == 0) {
      #pragma unroll
      for (int j = 0; j < 13; ++j) {
        half8 bh = *(const half8*)(bp + j * 1024 + lane * 16);
        acc[j] = MFMAH(Ah0, bh, acc[j]);
      }
    } else {
      #pragma unroll
      for (int j = 0; j < 13; ++j) {
        half8 bh = *(const half8*)(bp + j * 1024 + lane * 16);
        acc[j] = MFMAH(Ah1, bh, acc[j]);
      }
    }
    __builtin_amdgcn_s_setprio(0);
    SBAR0();
    if (kk < 14) {
      stage(ldsb + ((kk + 2) % 3) * 13312, kk + 2);    // 4 vmem; buffer last read at kk-1
      SBAR0();
      if ((kk & 1) == 0) {                             // A(kk+2) hi -> slot0: 1 vmem
        Ah0 = *(const half8*)(WvA + ((size_t)((kk + 2) * 2 + 0) * 128 + rbase) * 512 + lane * 8);
      } else {                                         // A(kk+2) hi -> slot1
        Ah1 = *(const half8*)(WvA + ((size_t)((kk + 2) * 2 + 0) * 128 + rbase) * 512 + lane * 8);
      }
      SBAR0();
    }
  }

  // epilogue: per-wave direct S1/S2/S3 (16 oc per wave).
  // C/D layout: hw-col = lane&15, oc-row-in-frag = (lane>>4)*4 + r.
  float attw[13];
  #pragma unroll
  for (int j = 0; j < 13; ++j) attw[j] = attn_sh[j * 16 + (lane & 15)];
  #pragma unroll
  for (int r = 0; r < 4; ++r) {
    float u = 0.f, vsq = 0.f, wsum = 0.f;
    #pragma unroll
    for (int j = 0; j < 13; ++j) {
      float v = acc[j][r];
      u += v;
      vsq = fmaf(v, v, vsq);
      wsum = fmaf(v, attw[j], wsum);
    }
    #pragma unroll
    for (int off = 8; off; off >>= 1) {
      u += __shfl_xor(u, off, 16);
      vsq += __shfl_xor(vsq, off, 16);
      wsum += __shfl_xor(wsum, off, 16);
    }
    if ((lane & 15) == 0) {
      int oc = rbase * 16 + (lane >> 4) * 4 + r;
      size_t base = (size_t)nd * OC + oc;
      S1[base] = u;
      S2[base] = vsq;
      S3[base] = wsum;
    }
  }
}

// ---------------- head: per (nd,oc) InstanceNorm + gelu + Wout reduce ----------------
__global__ void head_final(const float* __restrict__ S1, const float* __restrict__ S2,
                           const float* __restrict__ S3,
                           const float* __restrict__ gamma, const float* __restrict__ beta,
                           const float* __restrict__ Wout, const float* __restrict__ bout,
                           float* __restrict__ outs) {
  int nd = blockIdx.x;
  int t = threadIdx.x;
  int w = t >> 6, lane = t & 63;
  __shared__ float redp[16];
  float po[4] = {0.f, 0.f, 0.f, 0.f};
  #pragma unroll
  for (int i = 0; i < 8; ++i) {
    int oc = i * 256 + t;
    float m1 = S1[(size_t)nd * OC + oc] * INV196;
    float m2 = S2[(size_t)nd * OC + oc] * INV196;
    float var = m2 - m1 * m1;
    float rs = rsqrtf(var + 1e-5f);
    float xh = (S3[(size_t)nd * OC + oc] - m1) * rs * gamma[oc] + beta[oc];
    float ge = 0.5f * xh * (1.0f + erff(xh * 0.70710678118654752f));
    po[i >> 1] = fmaf(ge, Wout[oc], po[i >> 1]);
  }
  #pragma unroll
  for (int off = 32; off; off >>= 1) {
    #pragma unroll
    for (int o = 0; o < 4; ++o) po[o] += __shfl_down(po[o], off, 64);
  }
  if (lane == 0) {
    #pragma unroll
    for (int o = 0; o < 4; ++o) redp[w * 4 + o] = po[o];
  }
  __syncthreads();
  if (t < 4) {
    int o = t;
    float s = redp[o] + redp[4 + o] + redp[8 + o] + redp[12 + o] + bout[o];
    int n = nd >> 5, d = nd & 31;
    outs[o * 64 + n * 32 + d] = s;
  }
}

}  // namespace

extern "C" void kernel_launch(void* const* d_in, const int* in_sizes, int n_in,
                              void* d_out, int out_size, void* d_ws, size_t ws_size,
                              hipStream_t stream) {
  const float* x     = (const float*)d_in[0];
  const float* Wq    = (const float*)d_in[1];
  const float* Wk    = (const float*)d_in[2];
  const float* Wv    = (const float*)d_in[3];
  const float* gamma = (const float*)d_in[4];
  const float* beta  = (const float*)d_in[5];
  const float* Wout  = (const float*)d_in[6];
  const float* bout  = (const float*)d_in[7];
  float* out      = (float*)d_out;
  float* attn_out = out;            // (N,4,D,196) = 50176 floats
  float* outs     = out + 50176;    // (4,N,1,D)   = 256 floats

  float* ws = (float*)d_ws;
  _Float16*  WvA  = (_Float16*)ws;                      // 2097152 f16 -> [0, 1048576) floats
  _Float16*  xpH  = (_Float16*)(ws + 1048576);          // 7340032 f16 -> 3670016 floats
  float*     xm   = ws + 4718592;                       // 32768
  float*     dotb = ws + 4751360;                       // 57344
  float*     S1   = ws + 4808704;                       // 131072
  float*     S2   = ws + 4939776;                       // 131072
  float*     S3   = ws + 5070848;                       // 131072

  fat_prep<<<4608, 256, 0, stream>>>(x, Wv, WvA, xpH, xm);
  attn_dots<<<256, 256, 0, stream>>>(Wq, Wk, xm, xpH, dotb);
  moments_mfma<<<2048, 256, 0, stream>>>(WvA, xpH, dotb, attn_out, S1, S2, S3);
  head_final<<<64, 256, 0, stream>>>(S1, S2, S3, gamma, beta, Wout, bout, outs);
}

// Round 22
// 70.539 us; speedup vs baseline: 1.2782x; 1.2782x over previous
//
#include <hip/hip_runtime.h>
#include <math.h>

namespace {

constexpr int HW  = 196;
constexpr int HWP = 224;
constexpr int OC  = 2048;
constexpr float TEMP   = 0.35355339059327373f;  // 1/sqrt(KEY_DIM)
constexpr float INV196 = 1.0f / 196.0f;

typedef __attribute__((ext_vector_type(8))) _Float16 half8;
typedef __attribute__((ext_vector_type(4))) float f32x4;

__device__ __forceinline__ void gload_lds16(const void* g, void* l) {
  __builtin_amdgcn_global_load_lds(
      (const __attribute__((address_space(1))) void*)g,
      (__attribute__((address_space(3))) void*)l, 16, 0, 0);
}

#define MFMAH(a, b, c) __builtin_amdgcn_mfma_f32_16x16x32_f16((a), (b), (c), 0, 0, 0)
#define SBAR0() __builtin_amdgcn_sched_barrier(0)

// ================= K1: WvA prep (512 blocks) || pool (4096 blocks, XCD-affine) =================
__global__ __launch_bounds__(256) void fat_prep(
    const float* __restrict__ x, const float* __restrict__ Wv,
    _Float16* __restrict__ WvA,
    _Float16* __restrict__ xpH, float* __restrict__ xm) {
  __shared__ float tl[8][264];
  int bid = blockIdx.x;
  int t = threadIdx.x;
  if (bid < 512) {
    int kk = bid >> 5;
    int rq = bid & 31;
    int w = t >> 6, lane = t & 63;
    int r = rq * 4 + w;
    int oc = r * 16 + (lane & 15);
    int c0 = kk * 32 + (lane >> 4) * 8;
    const float* src = Wv + (size_t)oc * 512 + c0;
    float4 v0 = *(const float4*)src;
    float4 v1 = *(const float4*)(src + 4);
    float vals[8] = {v0.x, v0.y, v0.z, v0.w, v1.x, v1.y, v1.z, v1.w};
    half8 hi, lo;
    #pragma unroll
    for (int e = 0; e < 8; ++e) {
      _Float16 h = (_Float16)vals[e];
      hi[e] = h;
      lo[e] = (_Float16)(vals[e] - (float)h);
    }
    *(half8*)(WvA + ((size_t)(kk * 2 + 0) * 128 + r) * 512 + lane * 8) = hi;
    *(half8*)(WvA + ((size_t)(kk * 2 + 1) * 128 + r) * 512 + lane * 8) = lo;
  } else {
    int pb = bid - 512;
    int nd = (((pb >> 9) & 7) << 3) | (pb & 7);   // XCD-affine
    int cg = (pb >> 3) & 63;
    int n = nd >> 5, d = nd & 31;
    int c0 = cg * 8;
    int cl = t >> 5, s = t & 31;
    const float* xr = x + (((size_t)(n * 512 + c0 + cl)) * 32 + d) * 256;
    float4 va = *(const float4*)(xr + s * 8);
    float4 vb = *(const float4*)(xr + s * 8 + 4);
    *(float4*)&tl[cl][s * 8] = va;
    *(float4*)&tl[cl][s * 8 + 4] = vb;
    float rs = va.x + va.y + va.z + va.w + vb.x + vb.y + vb.z + vb.w;
    #pragma unroll
    for (int off = 16; off; off >>= 1) rs += __shfl_xor(rs, off, 32);
    if (s == 0) xm[nd * 512 + c0 + cl] = rs * (1.0f / 256.0f);
    __syncthreads();
    if (t < HWP) {
      int hw = t;
      half8 hi;
      if (hw < HW) {
        int y = hw / 14, xx = hw - y * 14;
        #pragma unroll
        for (int c = 0; c < 8; ++c) {
          const float* q = &tl[c][y * 16 + xx];
          float val = (q[0] + q[1] + q[2] + q[16] + q[17] + q[18] +
                       q[32] + q[33] + q[34]) * (1.0f / 9.0f);
          hi[c] = (_Float16)val;
        }
      } else {
        #pragma unroll
        for (int c = 0; c < 8; ++c) hi[c] = (_Float16)0.f;
      }
      *(half8*)(xpH + ((size_t)nd * HWP + hw) * 512 + c0) = hi;
    }
  }
}

// ---------------- attn dots: dot[nd][o][hw] = qw[o] . xp_hi[hw]  (4 lanes per hw) ----------------
__global__ __launch_bounds__(256) void attn_dots(
    const float* __restrict__ Wq, const float* __restrict__ Wk,
    const float* __restrict__ xm,
    const _Float16* __restrict__ xpH, float* __restrict__ dotb) {
  int b = blockIdx.x;
  int nd = b >> 2, ch = b & 3;
  int t = threadIdx.x;
  __shared__ float xs[512];
  __shared__ float qsA[32];
  __shared__ float qw[2048];
  xs[t] = xm[nd * 512 + t];
  xs[t + 256] = xm[nd * 512 + t + 256];
  __syncthreads();
  {
    int k = t >> 3, j = t & 7;
    float p = 0.f;
    #pragma unroll 8
    for (int c = j; c < 512; c += 8) p = fmaf(Wq[k * 512 + c], xs[c], p);
    p += __shfl_xor(p, 4, 8);
    p += __shfl_xor(p, 2, 8);
    p += __shfl_xor(p, 1, 8);
    if (j == 0) qsA[k] = p;
  }
  __syncthreads();
  {
    int o = t >> 6;
    int c0 = (t & 63) * 8;
    float q[8];
    #pragma unroll
    for (int kd = 0; kd < 8; ++kd) q[kd] = qsA[o * 8 + kd];
    #pragma unroll
    for (int e = 0; e < 8; ++e) {
      float a = 0.f;
      #pragma unroll
      for (int kd = 0; kd < 8; ++kd)
        a = fmaf(q[kd], Wk[(size_t)(o * 8 + kd) * 512 + c0 + e], a);
      qw[o * 512 + c0 + e] = a;
    }
  }
  __syncthreads();
  if (t < 224) {
    int hwl = t >> 2, q = t & 3;
    int hw = ch * 56 + hwl;
    const _Float16* rh = xpH + ((size_t)nd * HWP + hw) * 512;
    float d0 = 0.f, d1 = 0.f, d2 = 0.f, d3 = 0.f;
    #pragma unroll
    for (int k = 0; k < 16; ++k) {
      int cb = q * 8 + k * 32;           // interleaved c-blocks: conflict-free qw banks
      half8 h = *(const half8*)(rh + cb);
      #pragma unroll
      for (int e = 0; e < 8; ++e) {
        float xv = (float)h[e];
        d0 = fmaf(qw[cb + e], xv, d0);
        d1 = fmaf(qw[512 + cb + e], xv, d1);
        d2 = fmaf(qw[1024 + cb + e], xv, d2);
        d3 = fmaf(qw[1536 + cb + e], xv, d3);
      }
    }
    d0 += __shfl_xor(d0, 1, 4); d0 += __shfl_xor(d0, 2, 4);
    d1 += __shfl_xor(d1, 1, 4); d1 += __shfl_xor(d1, 2, 4);
    d2 += __shfl_xor(d2, 1, 4); d2 += __shfl_xor(d2, 2, 4);
    d3 += __shfl_xor(d3, 1, 4); d3 += __shfl_xor(d3, 2, 4);
    float r = (q == 0) ? d0 : (q == 1) ? d1 : (q == 2) ? d2 : d3;
    dotb[((size_t)nd * 4 + q) * HWP + hw] = r * TEMP;
  }
}

// ---------------- moments + inline softmax + attention-weighted sum (1-product f16 MFMA) ----------
// r20's validated single-barrier 3-buffer pipeline (wave = 2 oc-rows x 13 j), with the
// s_setprio(1/0) pair REMOVED (suspected cross-block priority inversion at 2 blocks/CU).
// Ledger identical to r20: steady vmcnt(6), kk=15 vmcnt(0).
__global__ __launch_bounds__(256, 2) void moments_mfma(
    const _Float16* __restrict__ WvA, const _Float16* __restrict__ xpH,
    const float* __restrict__ dotb, float* __restrict__ attn_out,
    float* __restrict__ S1, float* __restrict__ S2, float* __restrict__ S3) {
  int bid = blockIdx.x;
  int ob = (bid >> 3) & 15;
  int nd = ((bid >> 7) << 3) | (bid & 7);
  int o = ob >> 2;
  int t = threadIdx.x;
  int w = t >> 6, lane = t & 63;
  int rbase = ob * 8 + w * 2;            // this wave's 2 oc-rows
  __shared__ char ldsb[39936];           // 3 x 13312 B buffers: [j(13)][granule(64)][16B]
  __shared__ float attn_sh[HWP];
  __shared__ float redm[4];
  __shared__ float reds[4];
  const _Float16* xph = xpH + (size_t)nd * HWP * 512;

  float vdot = (t < HW) ? dotb[((size_t)nd * 4 + o) * HWP + t] : -3.0e38f;

  f32x4 acc[2][13];
  #pragma unroll
  for (int f = 0; f < 2; ++f)
    #pragma unroll
    for (int j = 0; j < 13; ++j) acc[f][j] = (f32x4){0.f, 0.f, 0.f, 0.f};

  // stage one 13312B kk-tile: every wave issues exactly 4 gload_lds instructions
  auto stage = [&](char* buf, int kk) {
    #pragma unroll
    for (int i = 0; i < 3; ++i) {
      int G = i * 256 + t;
      int j = G >> 6, g = G & 63;
      int hwl = g & 15, bb = g >> 4;
      const _Float16* src = xph + (size_t)(j * 16 + hwl) * 512 + kk * 32 + bb * 8;
      gload_lds16((const void*)src, (void*)(buf + G * 16));
    }
    if (lane < 16) {
      int G = 768 + w * 16 + lane;
      int g = G & 63;
      int hwl = g & 15, bb = g >> 4;
      const _Float16* src = xph + (size_t)(12 * 16 + hwl) * 512 + kk * 32 + bb * 8;
      gload_lds16((const void*)src, (void*)(buf + G * 16));
    }
  };

  stage(ldsb, 0);                        // s(0) -> buf0: 4 vmem/wave
  SBAR0();
  stage(ldsb + 13312, 1);                // s(1) -> buf1: 4
  SBAR0();
  half8 Ah0[2], Ah1[2];
  #pragma unroll
  for (int f = 0; f < 2; ++f)            // A(0) hi -> slot0: 2 vmem
    Ah0[f] = *(const half8*)(WvA + ((size_t)(0 * 2 + 0) * 128 + rbase + f) * 512 + lane * 8);
  #pragma unroll
  for (int f = 0; f < 2; ++f)            // A(1) hi -> slot1: 2 vmem
    Ah1[f] = *(const half8*)(WvA + ((size_t)(1 * 2 + 0) * 128 + rbase + f) * 512 + lane * 8);
  SBAR0();

  // ---- inline softmax (exact division); lgkm-only barriers keep vmem loads in flight ----
  {
    float m = vdot;
    #pragma unroll
    for (int off = 32; off; off >>= 1) m = fmaxf(m, __shfl_xor(m, off, 64));
    if (lane == 0) redm[w] = m;
    asm volatile("s_waitcnt lgkmcnt(0)" ::: "memory");
    __builtin_amdgcn_s_barrier();
    float bm = fmaxf(fmaxf(redm[0], redm[1]), fmaxf(redm[2], redm[3]));
    float e = (t < HW) ? expf(vdot - bm) : 0.f;
    float s = e;
    #pragma unroll
    for (int off = 32; off; off >>= 1) s += __shfl_xor(s, off, 64);
    if (lane == 0) reds[w] = s;
    asm volatile("s_waitcnt lgkmcnt(0)" ::: "memory");
    __builtin_amdgcn_s_barrier();
    float bs = reds[0] + reds[1] + reds[2] + reds[3];
    float a = (t < HW) ? (e / bs) : 0.f;
    if (t < HWP) attn_sh[t] = a;
    if ((ob & 3) == 0 && t < HW) {
      int n = nd >> 5, d = nd & 31;
      attn_out[(((size_t)n * 4 + o) * 32 + d) * HW + t] = a;
    }
  }

  // ---- main pipelined loop: ONE barrier per iteration ----
  #pragma unroll
  for (int kk = 0; kk < 16; ++kk) {
    if (kk == 15) {
      asm volatile("s_waitcnt vmcnt(0) lgkmcnt(0)" ::: "memory");
    } else {
      asm volatile("s_waitcnt vmcnt(6) lgkmcnt(0)" ::: "memory");
    }
    __builtin_amdgcn_s_barrier();
    SBAR0();
    const char* bp = ldsb + (kk % 3) * 13312;
    if ((kk & 1) == 0) {
      #pragma unroll
      for (int j = 0; j < 13; ++j) {
        half8 bh = *(const half8*)(bp + j * 1024 + lane * 16);
        acc[0][j] = MFMAH(Ah0[0], bh, acc[0][j]);
        acc[1][j] = MFMAH(Ah0[1], bh, acc[1][j]);
      }
    } else {
      #pragma unroll
      for (int j = 0; j < 13; ++j) {
        half8 bh = *(const half8*)(bp + j * 1024 + lane * 16);
        acc[0][j] = MFMAH(Ah1[0], bh, acc[0][j]);
        acc[1][j] = MFMAH(Ah1[1], bh, acc[1][j]);
      }
    }
    SBAR0();
    if (kk < 14) {
      stage(ldsb + ((kk + 2) % 3) * 13312, kk + 2);    // 4 vmem; buffer last read at kk-1
      SBAR0();
      if ((kk & 1) == 0) {                             // A(kk+2) hi -> slot0: 2 vmem
        #pragma unroll
        for (int f = 0; f < 2; ++f)
          Ah0[f] = *(const half8*)(WvA + ((size_t)((kk + 2) * 2 + 0) * 128 + rbase + f) * 512 + lane * 8);
      } else {                                         // A(kk+2) hi -> slot1
        #pragma unroll
        for (int f = 0; f < 2; ++f)
          Ah1[f] = *(const half8*)(WvA + ((size_t)((kk + 2) * 2 + 0) * 128 + rbase + f) * 512 + lane * 8);
      }
      SBAR0();
    }
  }

  // epilogue: per-wave direct S1/S2/S3 (no cross-wave reduction needed).
  // C/D layout: hw-col = lane&15, oc-row-in-frag = (lane>>4)*4 + r.
  float attw[13];
  #pragma unroll
  for (int j = 0; j < 13; ++j) attw[j] = attn_sh[j * 16 + (lane & 15)];
  #pragma unroll
  for (int f = 0; f < 2; ++f) {
    #pragma unroll
    for (int r = 0; r < 4; ++r) {
      float u = 0.f, vsq = 0.f, wsum = 0.f;
      #pragma unroll
      for (int j = 0; j < 13; ++j) {
        float v = acc[f][j][r];
        u += v;
        vsq = fmaf(v, v, vsq);
        wsum = fmaf(v, attw[j], wsum);
      }
      #pragma unroll
      for (int off = 8; off; off >>= 1) {
        u += __shfl_xor(u, off, 16);
        vsq += __shfl_xor(vsq, off, 16);
        wsum += __shfl_xor(wsum, off, 16);
      }
      if ((lane & 15) == 0) {
        int oc = (rbase + f) * 16 + (lane >> 4) * 4 + r;
        size_t base = (size_t)nd * OC + oc;
        S1[base] = u;
        S2[base] = vsq;
        S3[base] = wsum;
      }
    }
  }
}

// ---------------- head: per (nd,oc) InstanceNorm + gelu + Wout reduce ----------------
__global__ void head_final(const float* __restrict__ S1, const float* __restrict__ S2,
                           const float* __restrict__ S3,
                           const float* __restrict__ gamma, const float* __restrict__ beta,
                           const float* __restrict__ Wout, const float* __restrict__ bout,
                           float* __restrict__ outs) {
  int nd = blockIdx.x;
  int t = threadIdx.x;
  int w = t >> 6, lane = t & 63;
  __shared__ float redp[16];
  float po[4] = {0.f, 0.f, 0.f, 0.f};
  #pragma unroll
  for (int i = 0; i < 8; ++i) {
    int oc = i * 256 + t;
    float m1 = S1[(size_t)nd * OC + oc] * INV196;
    float m2 = S2[(size_t)nd * OC + oc] * INV196;
    float var = m2 - m1 * m1;
    float rs = rsqrtf(var + 1e-5f);
    float xh = (S3[(size_t)nd * OC + oc] - m1) * rs * gamma[oc] + beta[oc];
    float ge = 0.5f * xh * (1.0f + erff(xh * 0.70710678118654752f));
    po[i >> 1] = fmaf(ge, Wout[oc], po[i >> 1]);
  }
  #pragma unroll
  for (int off = 32; off; off >>= 1) {
    #pragma unroll
    for (int o = 0; o < 4; ++o) po[o] += __shfl_down(po[o], off, 64);
  }
  if (lane == 0) {
    #pragma unroll
    for (int o = 0; o < 4; ++o) redp[w * 4 + o] = po[o];
  }
  __syncthreads();
  if (t < 4) {
    int o = t;
    float s = redp[o] + redp[4 + o] + redp[8 + o] + redp[12 + o] + bout[o];
    int n = nd >> 5, d = nd & 31;
    outs[o * 64 + n * 32 + d] = s;
  }
}

}  // namespace

extern "C" void kernel_launch(void* const* d_in, const int* in_sizes, int n_in,
                              void* d_out, int out_size, void* d_ws, size_t ws_size,
                              hipStream_t stream) {
  const float* x     = (const float*)d_in[0];
  const float* Wq    = (const float*)d_in[1];
  const float* Wk    = (const float*)d_in[2];
  const float* Wv    = (const float*)d_in[3];
  const float* gamma = (const float*)d_in[4];
  const float* beta  = (const float*)d_in[5];
  const float* Wout  = (const float*)d_in[6];
  const float* bout  = (const float*)d_in[7];
  float* out      = (float*)d_out;
  float* attn_out = out;            // (N,4,D,196) = 50176 floats
  float* outs     = out + 50176;    // (4,N,1,D)   = 256 floats

  float* ws = (float*)d_ws;
  _Float16*  WvA  = (_Float16*)ws;                      // 2097152 f16 -> [0, 1048576) floats
  _Float16*  xpH  = (_Float16*)(ws + 1048576);          // 7340032 f16 -> 3670016 floats
  float*     xm   = ws + 4718592;                       // 32768
  float*     dotb = ws + 4751360;                       // 57344
  float*     S1   = ws + 4808704;                       // 131072
  float*     S2   = ws + 4939776;                       // 131072
  float*     S3   = ws + 5070848;                       // 131072

  fat_prep<<<4608, 256, 0, stream>>>(x, Wv, WvA, xpH, xm);
  attn_dots<<<256, 256, 0, stream>>>(Wq, Wk, xm, xpH, dotb);
  moments_mfma<<<1024, 256, 0, stream>>>(WvA, xpH, dotb, attn_out, S1, S2, S3);
  head_final<<<64, 256, 0, stream>>>(S1, S2, S3, gamma, beta, Wout, bout, outs);
}